// Round 7
// baseline (213.012 us; speedup 1.0000x reference)
//
#include <hip/hip_runtime.h>
#include <stdint.h>

// pairs_of_pairs: fused [concat -> conv1x1+relu x3]
// B=32, C=64, S=64, CC=128, OC=256. 2016 rows of 64 positions.
// R6: 1 row/block, 256 thr (4 waves), wave = 128o x 32pos (2 o-grp x 2 pos-grp).
// Rationale: R5 was LDS-traffic+latency bound (every wave read full 64KB X per
// layer; 1 block/CU at 64KB since usable LDS pool ~96-112KB, session-measured).
// Now: wave reads only its 32-pos X slice (16KB) -> 4x less LDS read volume
// per row; X = exactly 32KB -> 3 blocks/CU = 3 waves/SIMD latency cover.
// X = 4 chunks [64pos][64ch] bf16 (8KB each); rolled-x never stored (layer-0
// k>=192 reads chunk2 at pos-d mod 64); build stg buffers alias chunk3/chunk2.

typedef __attribute__((ext_vector_type(8))) __bf16 bf16x8;
typedef __attribute__((ext_vector_type(4))) float f32x4;
typedef __attribute__((ext_vector_type(4))) unsigned short u16x4;
typedef __attribute__((ext_vector_type(8))) unsigned short u16x8;

__device__ __forceinline__ unsigned short f2bf(float f) {
  unsigned int u = __builtin_bit_cast(unsigned int, f);
  u += 0x7FFFu + ((u >> 16) & 1u);
  return (unsigned short)(u >> 16);
}

// X: 4 chunk regions of [64 pos][64 ch] bf16 (4096 elems each).
// Within chunk: 16B-slot = pos*8 + ((c6/8) ^ pos)&7 -> ~2-way max on
// ds_read_b128 B-fragments and epilogue writes.
__device__ __forceinline__ int xaddr(int pos, int c) {
  int slot = (pos << 3) + ((((c & 63) >> 3) ^ pos) & 7);
  return ((c >> 6) << 12) + (slot << 3) + (c & 7);
}

__global__ void wconv_kernel(const float* __restrict__ W1, const float* __restrict__ W2,
                             const float* __restrict__ W3, unsigned short* __restrict__ wb) {
  int i = (blockIdx.x * 256 + threadIdx.x) * 4;  // grid 64 -> 65536 per layer
  const float* Ws[3] = {W1, W2, W3};
#pragma unroll
  for (int L = 0; L < 3; ++L) {
    f32x4 a = *(const f32x4*)(Ws[L] + i);
    u16x4 p;
#pragma unroll
    for (int v = 0; v < 4; ++v) p[v] = f2bf(a[v]);
    *(u16x4*)(wb + L * 65536 + i) = p;
  }
}

__global__ __launch_bounds__(256, 2)
void fused_kernel(const float* __restrict__ x, const float* __restrict__ xc,
                  const unsigned short* __restrict__ wb,
                  const float* __restrict__ b1, const float* __restrict__ b2,
                  const float* __restrict__ b3, float* __restrict__ out) {
  __shared__ __align__(16) unsigned char lraw[32768];
  unsigned short* X = (unsigned short*)lraw;              // 32KB, 4 chunks of 8KB
  float* bounce = (float*)lraw;                           // 32KB epilogue reuse
  unsigned short* stgA = (unsigned short*)lraw + 12288;   // 8KB = chunk3 region
  unsigned short* stgB = (unsigned short*)lraw + 8192;    // 8KB = chunk2 region

  const int r = blockIdx.x;       // 0..2015
  const int b = r / 63;
  const int dd = r % 63;
  const int d = dd + 1;
  const int tid = threadIdx.x;    // 0..255
  const int lane = tid & 63;
  const int g16 = lane >> 4;
  const int l16 = lane & 15;
  const int wv = tid >> 6;        // wave 0..3
  const int wo = wv >> 1;         // o-group: o in [wo*128, wo*128+128)
  const int wp = wv & 1;          // pos-group: pos in [wp*32, wp*32+32)

  // ---------------- build layer-0 input tile (3 rounds) ----------------
  // rd 0: xc ch0-63 -> stgA | rd 1: xc ch64-127 -> stgB | rd 2: x -> stgA.
  // Transpose rd k writes chunk k. Rolled chunk never stored.
  // Safety: stgA=chunk3 (never a transpose target), stgB=chunk2 (written only
  // by rd2's transpose, after barrier B2, when stgB is dead).
  auto ldrnd = [&](int ck, f32x4 ld[4]) {
#pragma unroll
    for (int it = 0; it < 4; ++it) {
      int u = it * 256 + tid, cc = u >> 4, i4 = (u & 15) << 2;
      const float* src = (ck < 2)
          ? xc + (((b * 128 + ck * 64 + cc) * 63) + dd) * 64 + i4
          : x + (b * 64 + cc) * 64 + i4;
      ld[it] = *(const f32x4*)src;
    }
  };

  f32x4 ld[4];
  ldrnd(0, ld);
  for (int rd = 0; rd < 3; ++rd) {
    unsigned short* sb = (rd == 1) ? stgB : stgA;
#pragma unroll
    for (int it = 0; it < 4; ++it) {   // regs -> stg (bf16 [c][i])
      int u = it * 256 + tid, cc = u >> 4, i4 = (u & 15) << 2;
      u16x4 p;
#pragma unroll
      for (int v = 0; v < 4; ++v) p[v] = f2bf(ld[it][v]);
      *(u16x4*)&sb[cc * 64 + i4] = p;
    }
    if (rd < 2) ldrnd(rd + 1, ld);     // prefetch next round's globals
    __syncthreads();
    // transpose sb -> X chunk rd
#pragma unroll
    for (int it = 0; it < 2; ++it) {
      int u = it * 256 + tid;
      int i = u & 63;                  // position
      int c0 = (u >> 6) << 3;          // 0,8,...,56
      u16x8 p;
#pragma unroll
      for (int j = 0; j < 8; ++j) p[j] = sb[(c0 + j) * 64 + i];
      *(u16x8*)&X[xaddr(i, rd * 64 + c0)] = p;
    }
  }
  __syncthreads();  // build complete before layer-0 reads

  // ---------------- 3 fused conv1x1+relu layers ----------------
  for (int layer = 0; layer < 3; ++layer) {
    const unsigned short* wl = wb + layer * 65536;
    const float* bias = (layer == 0) ? b1 : (layer == 1) ? b2 : b3;
    const bool al3 = (layer == 0);     // layer-0 k in [192,256) aliases chunk2

    f32x4 acc[8][2] = {};              // [mf][nf], wave tile = 128 o x 32 pos
    const int ow = wo * 128;

#pragma unroll 1
    for (int kk = 0; kk < 8; ++kk) {
      int kb = kk * 32 + g16 * 8;      // lane-group's k-base
      bool a3 = al3 && (kk >= 6);
      int cc = a3 ? (128 + (kb & 63)) : kb;   // aliased -> chunk2 region
      bf16x8 bfr[2];
#pragma unroll
      for (int nf = 0; nf < 2; ++nf) {
        int pos = wp * 32 + nf * 16 + l16;
        int ie = a3 ? ((pos - d) & 63) : pos;
        bfr[nf] = __builtin_bit_cast(bf16x8, *(const u16x8*)&X[xaddr(ie, cc)]);
      }
      bf16x8 afr[8];
#pragma unroll
      for (int mf = 0; mf < 8; ++mf)
        afr[mf] = __builtin_bit_cast(
            bf16x8, *(const u16x8*)(wl + (ow + mf * 16 + l16) * 256 + kb));
#pragma unroll
      for (int mf = 0; mf < 8; ++mf) {
        acc[mf][0] = __builtin_amdgcn_mfma_f32_16x16x32_bf16(afr[mf], bfr[0], acc[mf][0], 0, 0, 0);
        acc[mf][1] = __builtin_amdgcn_mfma_f32_16x16x32_bf16(afr[mf], bfr[1], acc[mf][1], 0, 0, 0);
      }
    }
    __syncthreads();  // all waves done reading X before overwrite

    if (layer < 2) {
      // bias + relu -> bf16 back into X (D frag: pos = l16 col, o = g16*4+v)
#pragma unroll
      for (int mf = 0; mf < 8; ++mf) {
        int o0 = ow + mf * 16 + g16 * 4;
        f32x4 bv = *(const f32x4*)(bias + o0);
#pragma unroll
        for (int nf = 0; nf < 2; ++nf) {
          int pos = wp * 32 + nf * 16 + l16;
          u16x4 p;
#pragma unroll
          for (int v = 0; v < 4; ++v)
            p[v] = f2bf(fmaxf(acc[mf][nf][v] + bv[v], 0.f));
          *(u16x4*)&X[xaddr(pos, o0)] = p;
        }
      }
      __syncthreads();
    } else {
      // final: bias+relu -> fp32 LDS bounce (X dead) -> f32x4 stores.
      // half h: o in [h*128, h*128+128) (32KB), written by waves wo==h.
#pragma unroll
      for (int h = 0; h < 2; ++h) {
        if (h) __syncthreads();          // h0 reads done before h1 writes
        if (wo == h) {
#pragma unroll
          for (int mf = 0; mf < 8; ++mf) {
            int olb = mf * 16 + g16 * 4;   // o - h*128
            f32x4 bv = *(const f32x4*)(bias + h * 128 + olb);
#pragma unroll
            for (int nf = 0; nf < 2; ++nf) {
              int pos = wp * 32 + nf * 16 + l16;
#pragma unroll
              for (int v = 0; v < 4; ++v) {
                int ol = olb + v;
                bounce[ol * 64 + (pos ^ ((ol & 7) << 2))] =
                    fmaxf(acc[mf][nf][v] + bv[v], 0.f);
              }
            }
          }
        }
        __syncthreads();
        // read back along pos, coalesced f32x4 global stores
#pragma unroll
        for (int q = 0; q < 8; ++q) {
          int u = q * 256 + tid;
          int oh = u >> 4;               // 0..127
          int pos4 = (u & 15) << 2;
          f32x4 vv = *(const f32x4*)&bounce[oh * 64 + (pos4 ^ ((oh & 7) << 2))];
          int o = h * 128 + oh;
          *(f32x4*)&out[(((b * 256 + o) * 63) + dd) * 64 + pos4] = vv;
        }
      }
    }
  }
}

extern "C" void kernel_launch(void* const* d_in, const int* in_sizes, int n_in,
                              void* d_out, int out_size, void* d_ws, size_t ws_size,
                              hipStream_t stream) {
  const float* x  = (const float*)d_in[0];
  const float* xc = (const float*)d_in[1];
  const float* W1 = (const float*)d_in[2];
  const float* b1 = (const float*)d_in[3];
  const float* W2 = (const float*)d_in[4];
  const float* b2 = (const float*)d_in[5];
  const float* W3 = (const float*)d_in[6];
  const float* b3 = (const float*)d_in[7];
  float* out = (float*)d_out;
  unsigned short* wb = (unsigned short*)d_ws;  // 3 x 256 x 256 bf16 = 384 KB

  wconv_kernel<<<64, 256, 0, stream>>>(W1, W2, W3, wb);
  fused_kernel<<<2016, 256, 0, stream>>>(x, xc, wb, b1, b2, b3, out);
}

// Round 8
// 133.924 us; speedup vs baseline: 1.5905x; 1.5905x over previous
//
#include <hip/hip_runtime.h>
#include <stdint.h>

// pairs_of_pairs: fused [concat -> conv1x1+relu x3]
// B=32, C=64, S=64, CC=128, OC=256. 2016 rows of 64 positions.
// R7: 1 row/block, 256 thr, 4 waves x (64o x 64pos) o-split only (A:MFMA=1:4;
// R6's 128o waves doubled weight loads per MFMA and died on vmem latency).
// LDS = 32KB total: layer-0 input = 3 regions [64pos][64ch] bf16 (24KB, rolled
// chunk aliased from x region at shifted pos); h (layers 1-2 input) overwrites
// all 32KB as [64pos][256ch]; final epilogue bounce aliases too.
// Build: direct global->reg->swizzled ds_write_b128 (no staging, 1 barrier).
// 8 barriers/block total (R5 had ~17).

typedef __attribute__((ext_vector_type(8))) __bf16 bf16x8;
typedef __attribute__((ext_vector_type(4))) float f32x4;
typedef __attribute__((ext_vector_type(4))) unsigned short u16x4;
typedef __attribute__((ext_vector_type(8))) unsigned short u16x8;

__device__ __forceinline__ unsigned short f2bf(float f) {
  unsigned int u = __builtin_bit_cast(unsigned int, f);
  u += 0x7FFFu + ((u >> 16) & 1u);
  return (unsigned short)(u >> 16);
}

// layer-0 regions: region r base = r*4096 elems; [64 pos][64 ch] swizzled:
// 16B-slot = p*8 + ((c6>>3)^p)&7  -> ~2-way max on reads (lanes = 16
// consecutive p) and build writes.
__device__ __forceinline__ int xa(int reg, int p, int c6) {
  return reg * 4096 + (p * 8 + (((c6 >> 3) ^ p) & 7)) * 8 + (c6 & 7);
}
// h layout (layers 1-2 input): [64 pos][256 ch] over all 16K elems:
// 16B-slot = p*32 + ((c>>3)^p)&31.
__device__ __forceinline__ int xh(int p, int c) {
  return (p * 32 + (((c >> 3) ^ p) & 31)) * 8 + (c & 7);
}

__global__ void wconv_kernel(const float* __restrict__ W1, const float* __restrict__ W2,
                             const float* __restrict__ W3, unsigned short* __restrict__ wb) {
  int i = (blockIdx.x * 256 + threadIdx.x) * 4;  // grid 64 -> 65536 per layer
  const float* Ws[3] = {W1, W2, W3};
#pragma unroll
  for (int L = 0; L < 3; ++L) {
    f32x4 a = *(const f32x4*)(Ws[L] + i);
    u16x4 p;
#pragma unroll
    for (int v = 0; v < 4; ++v) p[v] = f2bf(a[v]);
    *(u16x4*)(wb + L * 65536 + i) = p;
  }
}

__global__ __launch_bounds__(256, 2)
void fused_kernel(const float* __restrict__ x, const float* __restrict__ xc,
                  const unsigned short* __restrict__ wb,
                  const float* __restrict__ b1, const float* __restrict__ b2,
                  const float* __restrict__ b3, float* __restrict__ out) {
  __shared__ __align__(16) unsigned char lraw[32768];
  unsigned short* X = (unsigned short*)lraw;   // layer0 regions / h / bounce
  float* bounce = (float*)lraw;

  const int r = blockIdx.x;       // 0..2015
  const int b = r / 63;
  const int dd = r % 63;
  const int d = dd + 1;
  const int tid = threadIdx.x;    // 0..255
  const int lane = tid & 63;
  const int g16 = lane >> 4;
  const int l16 = lane & 15;
  const int wv = tid >> 6;        // wave 0..3, owns o in [wv*64, wv*64+64)

  // ---------------- build layer-0 input (no staging) ----------------
  // Thread (p, c-octet): 8 coalesced f32 loads (lanes = consecutive pos,
  // 256B segments) -> bf16 pack -> 1 swizzled ds_write_b128.
#pragma unroll
  for (int cn = 0; cn < 3; ++cn) {        // 0: xc ch0-63, 1: xc ch64-127, 2: x
#pragma unroll
    for (int it = 0; it < 2; ++it) {
      int s = it * 256 + tid;             // 0..511
      int p = s & 63;
      int c0 = (s >> 6) << 3;             // 0,8,...,56
      u16x8 v;
#pragma unroll
      for (int j = 0; j < 8; ++j) {
        float f = (cn < 2) ? xc[(((b * 128 + cn * 64 + c0 + j) * 63) + dd) * 64 + p]
                           : x[(b * 64 + c0 + j) * 64 + p];
        v[j] = f2bf(f);
      }
      *(u16x8*)&X[xa(cn, p, c0)] = v;
    }
  }
  __syncthreads();

  // ---------------- 3 fused conv1x1+relu layers ----------------
  const float* biases[3] = {b1, b2, b3};
#pragma unroll
  for (int layer = 0; layer < 3; ++layer) {
    const unsigned short* wl = wb + layer * 65536;
    const float* bias = biases[layer];

    f32x4 acc[4][4] = {};                 // [mf][nf], wave tile = 64o x 64pos
    const int ow = wv * 64;

#pragma unroll 2
    for (int kk = 0; kk < 8; ++kk) {
      int kb = kk * 32 + g16 * 8;         // lane-group's 8-wide k-base
      bf16x8 bfr[4];
#pragma unroll
      for (int nf = 0; nf < 4; ++nf) {
        int p = nf * 16 + l16;            // position
        int addr;
        if (layer > 0)      addr = xh(p, kb);
        else if (kb < 64)   addr = xa(0, p, kb);
        else if (kb < 128)  addr = xa(1, p, kb - 64);
        else if (kb < 192)  addr = xa(2, p, kb - 128);
        else                addr = xa(2, (p - d) & 63, kb - 192);  // rolled x
        bfr[nf] = __builtin_bit_cast(bf16x8, *(const u16x8*)&X[addr]);
      }
      bf16x8 afr[4];
#pragma unroll
      for (int mf = 0; mf < 4; ++mf)
        afr[mf] = __builtin_bit_cast(
            bf16x8, *(const u16x8*)(wl + (ow + mf * 16 + l16) * 256 + kb));
#pragma unroll
      for (int mf = 0; mf < 4; ++mf)
#pragma unroll
        for (int nf = 0; nf < 4; ++nf)
          acc[mf][nf] = __builtin_amdgcn_mfma_f32_16x16x32_bf16(afr[mf], bfr[nf], acc[mf][nf], 0, 0, 0);
    }
    __syncthreads();  // all waves done reading X/h before overwrite

    if (layer < 2) {
      // bias + relu -> bf16 h into X (D frag: pos = l16 col, o = g16*4+v row)
#pragma unroll
      for (int mf = 0; mf < 4; ++mf) {
        int o0 = ow + mf * 16 + g16 * 4;
        f32x4 bv = *(const f32x4*)(bias + o0);
#pragma unroll
        for (int nf = 0; nf < 4; ++nf) {
          int p = nf * 16 + l16;
          u16x4 pk;
#pragma unroll
          for (int v = 0; v < 4; ++v)
            pk[v] = f2bf(fmaxf(acc[mf][nf][v] + bv[v], 0.f));
          *(u16x4*)&X[xh(p, o0)] = pk;
        }
      }
      __syncthreads();
    } else {
      // final: bias+relu -> fp32 bounce (LDS dead) -> f32x4 coalesced stores.
      // pass covers o in [pass*128, pass*128+128) (32KB), written by wv>>1==pass.
#pragma unroll
      for (int pass = 0; pass < 2; ++pass) {
        if (pass) __syncthreads();        // pass-0 reads done before pass-1 writes
        if ((wv >> 1) == pass) {
#pragma unroll
          for (int mf = 0; mf < 4; ++mf) {
            int oh0 = (wv & 1) * 64 + mf * 16 + g16 * 4;   // o - pass*128
            f32x4 bv = *(const f32x4*)(bias + pass * 128 + oh0);
#pragma unroll
            for (int nf = 0; nf < 4; ++nf) {
              int p = nf * 16 + l16;
#pragma unroll
              for (int v = 0; v < 4; ++v) {
                int oh = oh0 + v;
                bounce[oh * 64 + (p ^ ((oh & 7) << 2))] =
                    fmaxf(acc[mf][nf][v] + bv[v], 0.f);
              }
            }
          }
        }
        __syncthreads();
        // read back along pos, coalesced f32x4 global stores
#pragma unroll
        for (int q = 0; q < 8; ++q) {
          int u = q * 256 + tid;          // 0..2047
          int oh = u >> 4;                // 0..127
          int p4 = (u & 15) << 2;
          f32x4 vv = *(const f32x4*)&bounce[oh * 64 + (p4 ^ ((oh & 7) << 2))];
          *(f32x4*)&out[(((b * 256 + pass * 128 + oh) * 63) + dd) * 64 + p4] = vv;
        }
      }
    }
  }
}

extern "C" void kernel_launch(void* const* d_in, const int* in_sizes, int n_in,
                              void* d_out, int out_size, void* d_ws, size_t ws_size,
                              hipStream_t stream) {
  const float* x  = (const float*)d_in[0];
  const float* xc = (const float*)d_in[1];
  const float* W1 = (const float*)d_in[2];
  const float* b1 = (const float*)d_in[3];
  const float* W2 = (const float*)d_in[4];
  const float* b2 = (const float*)d_in[5];
  const float* W3 = (const float*)d_in[6];
  const float* b3 = (const float*)d_in[7];
  float* out = (float*)d_out;
  unsigned short* wb = (unsigned short*)d_ws;  // 3 x 256 x 256 bf16 = 384 KB

  wconv_kernel<<<64, 256, 0, stream>>>(W1, W2, W3, wb);
  fused_kernel<<<2016, 256, 0, stream>>>(x, xc, wb, b1, b2, b3, out);
}